// Round 7
// baseline (570.619 us; speedup 1.0000x reference)
//
#include <hip/hip_runtime.h>
#include <math.h>

#define KS 48
#define TLEN 512
#define BN 1024
#define START_S 46
#define STOP_S 47
#define NEGV -10000.0f
#define PF 8   // emission prefetch depth

typedef float v2f __attribute__((ext_vector_type(2)));

__device__ __forceinline__ float bcast_lane0(float v) {
    return __builtin_bit_cast(float, __builtin_amdgcn_readfirstlane(__builtin_bit_cast(int, v)));
}
__device__ __forceinline__ float rlane(float v, int k) {
    return __builtin_bit_cast(float, __builtin_amdgcn_readlane(__builtin_bit_cast(int, v), k));
}

// wave argmax, first-index tie-break (matches jnp.argmax; validated rounds 1-7)
__device__ __forceinline__ void wargmax(float& bv, int& bi) {
    #pragma unroll
    for (int off = 32; off; off >>= 1) {
        float ov = __shfl_xor(bv, off, 64);
        int   oi = __shfl_xor(bi, off, 64);
        if (ov > bv || (ov == bv && oi < bi)) { bv = ov; bi = oi; }
    }
}

// grid = 1024, 1-wave blocks.
// ROUND-14 (fusion, take 2): R6 decomposition: vit=303us (1420cy/step, 49% VALU),
// fwd~210, bt~40; R5 fusion SUMMED because both chains used LDS and lgkmcnt is a
// SHARED counter -> any fwd ds wait drained vit's reads too; no interleave was
// possible. Fix: vit exchange via v_readlane (zero DS ops -> pure-register chain,
// R1 proved perf-neutral standalone), fwd keeps the LDS float4 path, and the two
// are hand-interleaved per group with fwd's ds_read issued TWO groups ahead
// (~150cy of vit register work between issue and consume > 120cy DS latency).
// Only fwd touches lgkmcnt now. All arithmetic value-identical to the validated
// R3/R5 bodies (absmax 0.0 for 6 rounds).
__global__ __launch_bounds__(64) void crf14(
    const float* __restrict__ feats,   // [B, T, K]
    const float* __restrict__ trans,   // [K, K]  trans[next, prev]
    const int*   __restrict__ tags,    // [B, T]
    float*       __restrict__ out,     // [B] nll | [B] path_score | [B*T] paths
    unsigned char* __restrict__ bp_g)  // [B, T, K] backpointer bytes (groups 0-6)
{
    const int lane = threadIdx.x;
    const bool act = lane < KS;

    __shared__ float xbuf[64];                     // fwd exchange only
    __shared__ __align__(16) unsigned char seg[128 * KS];  // 6 KB 2-group bp ring
    __shared__ unsigned char path_sh[TLEN];

    const int b = blockIdx.x;
    const float* fb = feats + (size_t)b * TLEN * KS;
    const int*   tb = tags + (size_t)b * TLEN;
    unsigned char* bpb = bp_g + (size_t)b * TLEN * KS;

    // ---- tables (masked trans row per next=lane; Erow = exp for fwd) ----
    float Erow[KS], Trow[KS];
    {
        const float* tr = trans + (act ? lane : 0) * KS;
        #pragma unroll
        for (int p = 0; p < KS; ++p) {
            float tv = act ? tr[p] : NEGV;
            if (lane == START_S) tv = NEGV;
            if (p == STOP_S)     tv = NEGV;
            Trow[p] = tv;
            Erow[p] = __expf(tv);
        }
    }
    float tstart = act ? trans[lane * KS + START_S] : NEGV;
    if (lane == START_S) tstart = NEGV;

    float alpha;                               // fwd state
    float vit = (lane == START_S) ? 0.0f : NEGV;   // vit state

    // ---- vit-only step (t=0 peel): scalar tree, values identical to the
    // validated v2f tree (same fmax/compare ops on the same w_p floats) ----
    auto vgroup = [&](float vprev, int g4, float& m, int& mi) {
        float w0 = rlane(vprev, g4 + 0) + Trow[g4 + 0];
        float w1 = rlane(vprev, g4 + 1) + Trow[g4 + 1];
        float w2 = rlane(vprev, g4 + 2) + Trow[g4 + 2];
        float w3 = rlane(vprev, g4 + 3) + Trow[g4 + 3];
        float m01 = fmaxf(w0, w1); int i01 = (w1 > w0) ? g4 + 1 : g4 + 0;
        float m23 = fmaxf(w2, w3); int i23 = (w3 > w2) ? g4 + 3 : g4 + 2;
        m  = fmaxf(m01, m23);
        mi = (m23 > m01) ? i23 : i01;
    };
    auto vmerge = [&](float bs[12], int ib[12], float& best, int& bi) {
        #pragma unroll
        for (int st = 0; st < 6; ++st) {
            float a = bs[2 * st], c2 = bs[2 * st + 1];
            int ia = ib[2 * st], ic = ib[2 * st + 1];
            bs[st] = fmaxf(a, c2); ib[st] = (c2 > a) ? ic : ia;
        }
        #pragma unroll
        for (int st = 0; st < 3; ++st) {
            float a = bs[2 * st], c2 = bs[2 * st + 1];
            int ia = ib[2 * st], ic = ib[2 * st + 1];
            bs[st] = fmaxf(a, c2); ib[st] = (c2 > a) ? ic : ia;
        }
        best = fmaxf(bs[0], bs[1]);
        bi   = (bs[1] > bs[0]) ? ib[1] : ib[0];
        bi   = (bs[2] > best) ? ib[2] : bi;
        best = fmaxf(best, bs[2]);
    };

    // ---- t=0 peel: one row-0 load feeds both scans ----
    {
        float r0 = act ? fb[lane] : 0.0f;
        alpha = (act ? r0 : -INFINITY) + tstart;
        float bs[12]; int ib[12];
        #pragma unroll
        for (int gg = 0; gg < 12; ++gg) vgroup(vit, 4 * gg, bs[gg], ib[gg]);
        float best; int bi;
        vmerge(bs, ib, best, bi);
        if (act) seg[0 * KS + lane] = (unsigned char)bi;
        vit = best + r0;
    }

    // ---- fused step: fwd (LDS float4 path) interleaved with vit (readlane) ----
    auto fused = [&](float emv, int t) {
        const float vprev = vit;
        // fwd head: get the DS pipe moving first
        float s  = bcast_lane0(alpha);       // lane-0 alpha finite: valid shift
        float ue = __expf(alpha - s);        // -inf lanes -> 0
        xbuf[lane] = ue;                     // same-wave in-order LDS: no barrier
        const float4* uu = (const float4*)xbuf;
        float4 Ua = uu[0];                   // reads issued 2 groups ahead of use:
        float4 Ub = uu[1];                   // ~150cy of vit work covers ~120cy DS
        v2f acc0 = {0.f, 0.f}, acc1 = {0.f, 0.f};
        float bs[12]; int ib[12];
        #pragma unroll
        for (int gg = 0; gg < 12; ++gg) {
            float4 Un;
            if (gg < 10) Un = uu[gg + 2];    // issue next fwd read
            vgroup(vprev, 4 * gg, bs[gg], ib[gg]);   // register-only vit work
            v2f ua = {Ua.x, Ua.y}, ub = {Ua.z, Ua.w};
            v2f ea = {Erow[4 * gg + 0], Erow[4 * gg + 1]};
            v2f eb = {Erow[4 * gg + 2], Erow[4 * gg + 3]};
            acc0 = __builtin_elementwise_fma(ua, ea, acc0);
            acc1 = __builtin_elementwise_fma(ub, eb, acc1);
            Ua = Ub; Ub = Un;
        }
        float best; int bi;
        vmerge(bs, ib, best, bi);
        alpha = emv + s + __logf((acc0.x + acc0.y) + (acc1.x + acc1.y));
        if (act) seg[(t & 127) * KS + lane] = (unsigned char)bi;  // LDS ring
        vit = best + emv;
    };

    // ---- main loop t=1..511: shared em prefetch, fused steps ----
    float em[PF];
    #pragma unroll
    for (int j = 0; j < PF; ++j)
        em[j] = act ? fb[(1 + j) * KS + lane] : 0.0f;
    for (int c = 0; c < 63; ++c) {
        const int t0 = 1 + c * PF;
        float em_n[PF];
        #pragma unroll
        for (int j = 0; j < PF; ++j) {
            int tf = t0 + PF + j;
            em_n[j] = (act && tf < TLEN) ? fb[tf * KS + lane] : 0.0f;
        }
        #pragma unroll
        for (int j = 0; j < PF; ++j) fused(em[j], t0 + j);
        // flush completed bp group g=c>>3 (chunk c=8g+7 ends at t=64g+64,
        // which lands in the OTHER ring half -> no overwrite hazard).
        if ((c & 7) == 7 && c < 56) {
            const int gr = c >> 3;
            const float4* s4 = (const float4*)(seg + (gr & 1) * 64 * KS);
            float4* d4 = (float4*)(bpb + (size_t)gr * 64 * KS);
            #pragma unroll
            for (int i = 0; i < 3; ++i)
                d4[lane + 64 * i] = s4[lane + 64 * i];   // 3 KB burst
        }
        #pragma unroll
        for (int j = 0; j < PF; ++j) em[j] = em_n[j];
    }
    #pragma unroll
    for (int j = 0; j < 7; ++j)              // tail t=505..511
        fused(em[j], 505 + j);

    // drain flush stores before backtrace re-reads
    asm volatile("s_waitcnt vmcnt(0)" ::: "memory");

    // ---- forward terminal: logZ, gold score, nll ----
    float tstop = act ? trans[STOP_S * KS + lane] : NEGV;
    if (lane == STOP_S) tstop = NEGV;
    {
        float z = alpha + tstop;
        float mz = z;
        #pragma unroll
        for (int off = 32; off; off >>= 1)
            mz = fmaxf(mz, __shfl_xor(mz, off, 64));
        float se = __expf(z - mz);
        #pragma unroll
        for (int off = 32; off; off >>= 1)
            se += __shfl_xor(se, off, 64);
        float logZ = mz + __logf(se);

        float gs = 0.0f;
        for (int t = lane; t < TLEN; t += 64) {
            int tg = tb[t];
            int pg = (t == 0) ? START_S : tb[t - 1];
            gs += fb[t * KS + tg] + trans[tg * KS + pg];
        }
        #pragma unroll
        for (int off = 32; off; off >>= 1)
            gs += __shfl_xor(gs, off, 64);
        gs += trans[STOP_S * KS + tb[TLEN - 1]];

        if (lane == 0) out[b] = logZ - gs;
    }

    // ---- viterbi terminal + backtrace ----
    float term = act ? (vit + tstop) : -3.0e38f;
    float bv = term;
    int   bidx = act ? lane : 9999;
    wargmax(bv, bidx);
    if (lane == 0) out[BN + b] = bv;

    // group 7 (t=448..511) is resident in ring slots 64..127: chase it first.
    int tag = bidx;
    for (int t = 63; t >= 0; --t) {
        path_sh[448 + t] = (unsigned char)tag;
        tag = seg[(64 + t) * KS + tag];
    }
    for (int s = 6; s >= 0; --s) {
        float4 tmp[3];
        const float4* src = (const float4*)(bpb + (size_t)s * 64 * KS);
        #pragma unroll
        for (int i = 0; i < 3; ++i)
            tmp[i] = src[lane + 64 * i];
        // same-wave in-order DS: prior chase reads precede these writes
        float4* dst = (float4*)seg;              // lower half (slots 0..63)
        #pragma unroll
        for (int i = 0; i < 3; ++i)
            dst[lane + 64 * i] = tmp[i];
        for (int t = 63; t >= 0; --t) {
            path_sh[s * 64 + t] = (unsigned char)tag;  // tag at time s*64+t
            tag = seg[t * KS + tag];                   // -> tag at t-1
        }
    }
    __syncthreads();   // single wave: drains LDS before the read-back
    float* pout = out + 2 * BN + (size_t)b * TLEN;
    for (int t = lane; t < TLEN; t += 64)
        pout[t] = (float)path_sh[t];
}

extern "C" void kernel_launch(void* const* d_in, const int* in_sizes, int n_in,
                              void* d_out, int out_size, void* d_ws, size_t ws_size,
                              hipStream_t stream) {
    const float* feats = (const float*)d_in[0];
    const float* trans = (const float*)d_in[1];
    const int*   tags  = (const int*)d_in[2];
    float*       out   = (float*)d_out;
    (void)in_sizes; (void)n_in; (void)out_size; (void)ws_size;

    // workspace use: groups 0..6 of [B, T, K] bp bytes ≈ 22 MB (ws ≥ 100 MB)
    crf14<<<dim3(BN), dim3(64), 0, stream>>>(feats, trans, tags, out,
                                             (unsigned char*)d_ws);
}